// Round 10
// baseline (132.743 us; speedup 1.0000x reference)
//
#include <hip/hip_runtime.h>
#include <hip/hip_bf16.h>
#include <math.h>

#define EPS 1e-6f
#define N 64          // INPUT_SIZE == NUM_LEAVES
#define NLAYERS 63
#define SINK_ITERS 20
#define LOG2E 1.4426950408889634f

typedef __attribute__((ext_vector_type(8))) short bf16x8;   // 8 bf16 = 4 VGPRs
typedef __attribute__((ext_vector_type(4))) float f32x4;    // MFMA C/D

// fp32 -> bf16 round-to-nearest-even (bit pattern in ushort)
__device__ __forceinline__ unsigned short f2bf(float f) {
  unsigned int u = __float_as_uint(f);
  return (unsigned short)((u + 0x7FFFu + ((u >> 16) & 1u)) >> 16);
}

__device__ __forceinline__ bf16x8 pack8(float4 a, float4 b) {
  union { unsigned short us[8]; bf16x8 v; } u;
  u.us[0] = f2bf(a.x); u.us[1] = f2bf(a.y);
  u.us[2] = f2bf(a.z); u.us[3] = f2bf(a.w);
  u.us[4] = f2bf(b.x); u.us[5] = f2bf(b.y);
  u.us[6] = f2bf(b.z); u.us[7] = f2bf(b.w);
  return u.v;
}

// ---------------------------------------------------------------------------
// Kernel 1: Sinkhorn (scaling-vector form, single wave) + P -> MFMA B-fragment
// precompute (bf16) + per-layer scan constants. (Validated R8/R9 - unchanged.)
// B-frag for mfma_f32_16x16x32_bf16: lane l holds
// B[k = s*32 + (l>>4)*8 + j][n = t*16 + (l&15)], j=0..7.
// ---------------------------------------------------------------------------
__global__ __launch_bounds__(64) void sinkhorn_kernel(
    const float* __restrict__ logits,
    const float* __restrict__ weights,
    const float* __restrict__ biases,
    unsigned short* __restrict__ Pfrag,  // [8][64][8] bf16
    float* __restrict__ layers) {        // [63][8]: w0,w1,e0,e1,cl,cg,a,mode
  __shared__ float T[64 * 65 + 128];
  const int l = threadIdx.x;

  float K[64];
  {
    const float4* lr = (const float4*)(logits + (l << 6));
    #pragma unroll
    for (int q = 0; q < 16; ++q) {
      float4 t = lr[q];
      K[4*q+0] = exp2f(t.x * LOG2E);
      K[4*q+1] = exp2f(t.y * LOG2E);
      K[4*q+2] = exp2f(t.z * LOG2E);
      K[4*q+3] = exp2f(t.w * LOG2E);
    }
  }
  #pragma unroll
  for (int j = 0; j < 64; ++j) T[l * 65 + j] = K[j];
  __syncthreads();
  float KT[64];
  #pragma unroll
  for (int k = 0; k < 64; ++k) KT[k] = T[k * 65 + l];
  __syncthreads();

  float* Uv = &T[64 * 65];        // 16B-aligned
  float* Vv = &T[64 * 65 + 64];   // 16B-aligned
  const float4* Uv4 = (const float4*)Uv;
  const float4* Vv4 = (const float4*)Vv;
  Vv[l] = 1.0f;
  __syncthreads();

  float u = 1.0f;
  for (int it = 0; it < SINK_ITERS; ++it) {
    float s0 = 0.f, s1 = 0.f, s2 = 0.f, s3 = 0.f;
    #pragma unroll
    for (int q = 0; q < 16; ++q) {
      float4 v = Vv4[q];
      s0 = fmaf(K[4*q+0], v.x, s0);
      s1 = fmaf(K[4*q+1], v.y, s1);
      s2 = fmaf(K[4*q+2], v.z, s2);
      s3 = fmaf(K[4*q+3], v.w, s3);
    }
    u = 1.0f / ((s0 + s1) + (s2 + s3));
    __syncthreads();
    Uv[l] = u;
    __syncthreads();
    float c0 = 0.f, c1 = 0.f, c2 = 0.f, c3 = 0.f;
    #pragma unroll
    for (int q = 0; q < 16; ++q) {
      float4 uu = Uv4[q];
      c0 = fmaf(KT[4*q+0], uu.x, c0);
      c1 = fmaf(KT[4*q+1], uu.y, c1);
      c2 = fmaf(KT[4*q+2], uu.z, c2);
      c3 = fmaf(KT[4*q+3], uu.w, c3);
    }
    float v = 1.0f / ((c0 + c1) + (c2 + c3));
    __syncthreads();
    Vv[l] = v;
    __syncthreads();
  }

  #pragma unroll
  for (int j = 0; j < 64; ++j) T[l * 65 + j] = u * K[j] * Vv[j];
  __syncthreads();

  #pragma unroll
  for (int s = 0; s < 2; ++s)
    #pragma unroll
    for (int t = 0; t < 4; ++t) {
      union { unsigned short us[8]; bf16x8 v; } buf;
      #pragma unroll
      for (int j = 0; j < 8; ++j)
        buf.us[j] = f2bf(T[(s*32 + ((l >> 4) << 3) + j) * 65 + t*16 + (l & 15)]);
      *(bf16x8*)(Pfrag + (((s*4 + t) * 64 + l) << 3)) = buf.v;
    }

  if (l < NLAYERS) {
    float w0 = weights[l];
    float w1 = 1.0f - w0;
    float a  = biases[l];
    float e0 = 0.f, e1 = 0.f, cl = 0.f, cg = 0.f, mode;
    if (fabsf(a - 0.5f) < EPS) {
      mode = 0.0f;
    } else {
      float ae;
      if (a < 0.5f) { mode = 2.0f; ae = fminf(fmaxf(1.0f - a, -1.0f + EPS), 2.0f - EPS); }
      else          { mode = 1.0f; ae = a; }
      float pp = sqrtf(3.0f / fmaxf(2.0f - ae, EPS)) - 1.0f;
      if (ae >= 0.75f) { cl = 0.0f;            cg = 1.0f; }
      else             { cl = 3.0f - 4.0f*ae;  cg = 4.0f*ae - 2.0f; }
      e0 = 2.0f * w0 * pp;
      e1 = 2.0f * w1 * pp;
    }
    float* Lr = layers + l * 8;
    Lr[0] = w0; Lr[1] = w1; Lr[2] = e0; Lr[3] = e1;
    Lr[4] = cl; Lr[5] = cg; Lr[6] = a;  Lr[7] = mode;
  }
}

// ---------------------------------------------------------------------------
// F step (wave-uniform branch; Lp is a uniform address -> scalar loads).
// ---------------------------------------------------------------------------
__device__ __forceinline__ float F_step(float st, float leaf,
                                        const float* __restrict__ Lp) {
  float w0 = Lp[0], w1 = Lp[1], e0 = Lp[2], e1 = Lp[3];
  float cl = Lp[4], cg = Lp[5], av = Lp[6], mf = Lp[7];
  float xx = fminf(fmaxf(st,   EPS), 1.0f - EPS);
  float yy = fminf(fmaxf(leaf, EPS), 1.0f - EPS);
  float r;
  if (mf < 0.5f) {
    r = w0 * xx + w1 * yy;
  } else {
    if (mf > 1.5f) { xx = 1.0f - xx; yy = 1.0f - yy; }
    float lin = w0 * xx + w1 * yy;
    float g   = exp2f(e0 * log2f(xx) + e1 * log2f(yy));
    r = cl * lin + cg * g;
    if (mf > 1.5f) r = 1.0f - r;
  }
  return (r != r) ? av : r;   // NaN fallback to bias
}

// ---------------------------------------------------------------------------
// Kernel 2 (R10): R9's zero-barrier structure, but A-gather is TRANSIENT per
// m-tile: 4 float4 loads -> pack to bf16 frag -> raw regs die. Peak live set
// ~16 transient VGPR + ~40 misc VGPR + 64 AGPR (A/B frags) <= the
// launch_bounds(256,4) combined cap of 128 -- no spill (R9 spilled: its
// araw[4][2][2] array held 64 VGPRs live on top of the frags).
// All dependences wave-local; same-wave LDS write->read ordered by DS pipe.
// ---------------------------------------------------------------------------
__global__ __launch_bounds__(256, 4) void scan_kernel(
    const float* __restrict__ x,
    const unsigned short* __restrict__ Pfrag,
    const float* __restrict__ layers,
    float* __restrict__ out) {
  __shared__ float Lv[256 * 33];   // stride 33: scan reads 2-way = free
  const int tid = threadIdx.x;
  const int w = tid >> 6, l = tid & 63;
  const size_t rowbase = (size_t)blockIdx.x << 8;   // 256 rows per block

  // ---- B fragments (global, 8 KB, L2/L3-hot).
  bf16x8 B[2][4];
  #pragma unroll
  for (int s = 0; s < 2; ++s)
    #pragma unroll
    for (int t = 0; t < 4; ++t)
      B[s][t] = *(const bf16x8*)(Pfrag + (((s*4 + t) * 64 + l) << 3));

  // ---- A fragments: per-tile load + immediate pack (16 transient VGPRs).
  bf16x8 A[4][2];
  #pragma unroll
  for (int i = 0; i < 4; ++i) {
    const float* rp = x + (rowbase + (w << 6) + (i << 4) + (l & 15)) * 64
                        + ((l >> 4) << 3);
    float4 a0 = *(const float4*)(rp);
    float4 a1 = *(const float4*)(rp + 4);
    float4 b0 = *(const float4*)(rp + 32);
    float4 b1 = *(const float4*)(rp + 36);
    A[i][0] = pack8(a0, a1);
    A[i][1] = pack8(b0, b1);
  }

  float st = 0.f;
  #pragma unroll
  for (int half = 0; half < 2; ++half) {
    // ---- GEMM: n-cols half*32 .. half*32+31 -> fp32 leaves (own wave rows).
    #pragma unroll
    for (int i = 0; i < 4; ++i) {
      const int drow0 = (w << 6) + (i << 4) + ((l >> 4) << 2);
      #pragma unroll
      for (int tn = 0; tn < 2; ++tn) {
        const int t = (half << 1) + tn;    // global n-tile
        f32x4 acc = {0.f, 0.f, 0.f, 0.f};
        acc = __builtin_amdgcn_mfma_f32_16x16x32_bf16(A[i][0], B[0][t], acc, 0, 0, 0);
        acc = __builtin_amdgcn_mfma_f32_16x16x32_bf16(A[i][1], B[1][t], acc, 0, 0, 0);
        const int dcol = (tn << 4) + (l & 15);   // local col 0..31
        #pragma unroll
        for (int r = 0; r < 4; ++r)
          Lv[(drow0 + r) * 33 + dcol] = acc[r];
      }
    }
    // Same-wave producer/consumer: DS-pipe ordering + lgkmcnt, no barrier.
    if (half == 0) {
      st = Lv[tid * 33];                   // leaf 0 (fp32)
      #pragma unroll
      for (int j = 1; j < 32; ++j)
        st = F_step(st, Lv[tid * 33 + j], layers + (j - 1) * 8);
    } else {
      #pragma unroll
      for (int j = 32; j < 64; ++j)
        st = F_step(st, Lv[tid * 33 + (j - 32)], layers + (j - 1) * 8);
    }
  }

  out[rowbase + tid] = st;
}

// ---------------------------------------------------------------------------
extern "C" void kernel_launch(void* const* d_in, const int* in_sizes, int n_in,
                              void* d_out, int out_size, void* d_ws, size_t ws_size,
                              hipStream_t stream) {
  const float* x       = (const float*)d_in[0];
  const float* logits  = (const float*)d_in[1];
  const float* weights = (const float*)d_in[2];
  const float* biases  = (const float*)d_in[3];
  float* out = (float*)d_out;

  unsigned short* Pfrag = (unsigned short*)d_ws;              // 8 KB
  float* layers = (float*)((char*)d_ws + 8 * 64 * 8 * sizeof(unsigned short));

  const int batch = out_size;  // 262144

  hipLaunchKernelGGL(sinkhorn_kernel, dim3(1), dim3(64), 0, stream,
                     logits, weights, biases, Pfrag, layers);
  hipLaunchKernelGGL(scan_kernel, dim3(batch / 256), dim3(256), 0, stream,
                     x, Pfrag, layers, out);
}

// Round 11
// 125.326 us; speedup vs baseline: 1.0592x; 1.0592x over previous
//
#include <hip/hip_runtime.h>
#include <hip/hip_bf16.h>
#include <math.h>

#define EPS 1e-6f
#define N 64          // INPUT_SIZE == NUM_LEAVES
#define NLAYERS 63
#define SINK_ITERS 20
#define LOG2E 1.4426950408889634f

typedef __attribute__((ext_vector_type(8))) short bf16x8;   // 8 bf16 = 4 VGPRs
typedef __attribute__((ext_vector_type(4))) float f32x4;    // MFMA C/D

// Hardware transcendentals: single v_log_f32 / v_exp_f32. Inputs are clamped
// to [EPS, 1-EPS] (normal range) so no denormal/edge fixup is needed.
__device__ __forceinline__ float fast_log2(float v) {
#if __has_builtin(__builtin_amdgcn_logf)
  return __builtin_amdgcn_logf(v);
#else
  return log2f(v);
#endif
}
__device__ __forceinline__ float fast_exp2(float v) {
#if __has_builtin(__builtin_amdgcn_exp2f)
  return __builtin_amdgcn_exp2f(v);
#else
  return exp2f(v);
#endif
}

// fp32 -> bf16 round-to-nearest-even (bit pattern in ushort)
__device__ __forceinline__ unsigned short f2bf(float f) {
  unsigned int u = __float_as_uint(f);
  return (unsigned short)((u + 0x7FFFu + ((u >> 16) & 1u)) >> 16);
}

__device__ __forceinline__ bf16x8 pack8(float4 a, float4 b) {
  union { unsigned short us[8]; bf16x8 v; } u;
  u.us[0] = f2bf(a.x); u.us[1] = f2bf(a.y);
  u.us[2] = f2bf(a.z); u.us[3] = f2bf(a.w);
  u.us[4] = f2bf(b.x); u.us[5] = f2bf(b.y);
  u.us[6] = f2bf(b.z); u.us[7] = f2bf(b.w);
  return u.v;
}

// ---------------------------------------------------------------------------
// Kernel 1: Sinkhorn (scaling-vector form, single wave) + P -> MFMA B-fragment
// precompute (bf16) + per-layer scan constants. (Validated R8-R10.)
// B-frag for mfma_f32_16x16x32_bf16: lane l holds
// B[k = s*32 + (l>>4)*8 + j][n = t*16 + (l&15)], j=0..7.
// ---------------------------------------------------------------------------
__global__ __launch_bounds__(64) void sinkhorn_kernel(
    const float* __restrict__ logits,
    const float* __restrict__ weights,
    const float* __restrict__ biases,
    unsigned short* __restrict__ Pfrag,  // [8][64][8] bf16
    float* __restrict__ layers) {        // [63][8]: w0,w1,e0,e1,cl,cg,a,mode
  __shared__ float T[64 * 65 + 128];
  const int l = threadIdx.x;

  float K[64];
  {
    const float4* lr = (const float4*)(logits + (l << 6));
    #pragma unroll
    for (int q = 0; q < 16; ++q) {
      float4 t = lr[q];
      K[4*q+0] = fast_exp2(t.x * LOG2E);
      K[4*q+1] = fast_exp2(t.y * LOG2E);
      K[4*q+2] = fast_exp2(t.z * LOG2E);
      K[4*q+3] = fast_exp2(t.w * LOG2E);
    }
  }
  #pragma unroll
  for (int j = 0; j < 64; ++j) T[l * 65 + j] = K[j];
  __syncthreads();
  float KT[64];
  #pragma unroll
  for (int k = 0; k < 64; ++k) KT[k] = T[k * 65 + l];
  __syncthreads();

  float* Uv = &T[64 * 65];        // 16B-aligned
  float* Vv = &T[64 * 65 + 64];   // 16B-aligned
  const float4* Uv4 = (const float4*)Uv;
  const float4* Vv4 = (const float4*)Vv;
  Vv[l] = 1.0f;
  __syncthreads();

  float u = 1.0f;
  for (int it = 0; it < SINK_ITERS; ++it) {
    float s0 = 0.f, s1 = 0.f, s2 = 0.f, s3 = 0.f;
    #pragma unroll
    for (int q = 0; q < 16; ++q) {
      float4 v = Vv4[q];
      s0 = fmaf(K[4*q+0], v.x, s0);
      s1 = fmaf(K[4*q+1], v.y, s1);
      s2 = fmaf(K[4*q+2], v.z, s2);
      s3 = fmaf(K[4*q+3], v.w, s3);
    }
    u = 1.0f / ((s0 + s1) + (s2 + s3));
    __syncthreads();
    Uv[l] = u;
    __syncthreads();
    float c0 = 0.f, c1 = 0.f, c2 = 0.f, c3 = 0.f;
    #pragma unroll
    for (int q = 0; q < 16; ++q) {
      float4 uu = Uv4[q];
      c0 = fmaf(KT[4*q+0], uu.x, c0);
      c1 = fmaf(KT[4*q+1], uu.y, c1);
      c2 = fmaf(KT[4*q+2], uu.z, c2);
      c3 = fmaf(KT[4*q+3], uu.w, c3);
    }
    float v = 1.0f / ((c0 + c1) + (c2 + c3));
    __syncthreads();
    Vv[l] = v;
    __syncthreads();
  }

  #pragma unroll
  for (int j = 0; j < 64; ++j) T[l * 65 + j] = u * K[j] * Vv[j];
  __syncthreads();

  #pragma unroll
  for (int s = 0; s < 2; ++s)
    #pragma unroll
    for (int t = 0; t < 4; ++t) {
      union { unsigned short us[8]; bf16x8 v; } buf;
      #pragma unroll
      for (int j = 0; j < 8; ++j)
        buf.us[j] = f2bf(T[(s*32 + ((l >> 4) << 3) + j) * 65 + t*16 + (l & 15)]);
      *(bf16x8*)(Pfrag + (((s*4 + t) * 64 + l) << 3)) = buf.v;
    }

  if (l < NLAYERS) {
    float w0 = weights[l];
    float w1 = 1.0f - w0;
    float a  = biases[l];
    float e0 = 0.f, e1 = 0.f, cl = 0.f, cg = 0.f, mode;
    if (fabsf(a - 0.5f) < EPS) {
      mode = 0.0f;
    } else {
      float ae;
      if (a < 0.5f) { mode = 2.0f; ae = fminf(fmaxf(1.0f - a, -1.0f + EPS), 2.0f - EPS); }
      else          { mode = 1.0f; ae = a; }
      float pp = sqrtf(3.0f / fmaxf(2.0f - ae, EPS)) - 1.0f;
      if (ae >= 0.75f) { cl = 0.0f;            cg = 1.0f; }
      else             { cl = 3.0f - 4.0f*ae;  cg = 4.0f*ae - 2.0f; }
      e0 = 2.0f * w0 * pp;
      e1 = 2.0f * w1 * pp;
    }
    float* Lr = layers + l * 8;
    Lr[0] = w0; Lr[1] = w1; Lr[2] = e0; Lr[3] = e1;
    Lr[4] = cl; Lr[5] = cg; Lr[6] = a;  Lr[7] = mode;
  }
}

// ---------------------------------------------------------------------------
// F step: register-only, wave-uniform branch, hardware log2/exp2.
// ---------------------------------------------------------------------------
__device__ __forceinline__ float F_step(float st, float leaf,
                                        const float* __restrict__ Lp) {
  float w0 = Lp[0], w1 = Lp[1], e0 = Lp[2], e1 = Lp[3];
  float cl = Lp[4], cg = Lp[5], av = Lp[6], mf = Lp[7];
  float xx = fminf(fmaxf(st,   EPS), 1.0f - EPS);
  float yy = fminf(fmaxf(leaf, EPS), 1.0f - EPS);
  float r;
  if (mf < 0.5f) {
    r = w0 * xx + w1 * yy;
  } else {
    if (mf > 1.5f) { xx = 1.0f - xx; yy = 1.0f - yy; }
    float lin = w0 * xx + w1 * yy;
    float g   = fast_exp2(e0 * fast_log2(xx) + e1 * fast_log2(yy));
    r = cl * lin + cg * g;
    if (mf > 1.5f) r = 1.0f - r;
  }
  return (r != r) ? av : r;   // NaN fallback to bias
}

// ---------------------------------------------------------------------------
// Kernel 2 (R11): SWAPPED-OPERAND MFMA -> transposed D:
//   mfma(Bfrag, Afrag) = (A.B)^T, so D row = LEAF (quad*4+reg), col = batch
//   row (lane&15). Each lane's 4 acc regs = 4 consecutive leaves of ONE
//   batch row -> single ds_write_b128 per D-tile, and each thread reads its
//   full 32-leaf half with 8 ds_read_b128 BEFORE the F-chain (register-only
//   chain, no dependent 120-cyc LDS reads). Zero barriers (all wave-local).
//   Leaf buffer stride 36 floats -> 2-way banks (free), 36.9 KB LDS.
// ---------------------------------------------------------------------------
__global__ __launch_bounds__(256, 2) void scan_kernel(
    const float* __restrict__ x,
    const unsigned short* __restrict__ Pfrag,
    const float* __restrict__ layers,
    float* __restrict__ out) {
  __shared__ float Lv[256 * 36];
  const int tid = threadIdx.x;
  const int w = tid >> 6, l = tid & 63;
  const int q = l >> 4, c = l & 15;
  const size_t rowbase = (size_t)blockIdx.x << 8;   // 256 rows per block

  // ---- B fragments (Aop after swap): Pfrag, wave-uniform, L2-hot.
  bf16x8 Bf[2][4];
  #pragma unroll
  for (int s = 0; s < 2; ++s)
    #pragma unroll
    for (int t = 0; t < 4; ++t)
      Bf[s][t] = *(const bf16x8*)(Pfrag + (((s*4 + t) * 64 + l) << 3));

  // ---- A fragments (Bop after swap): transient per-tile gather from x.
  bf16x8 Af[4][2];
  #pragma unroll
  for (int i = 0; i < 4; ++i) {
    const float* rp = x + (rowbase + (w << 6) + (i << 4) + c) * 64 + (q << 3);
    float4 a0 = *(const float4*)(rp);
    float4 a1 = *(const float4*)(rp + 4);
    float4 b0 = *(const float4*)(rp + 32);
    float4 b1 = *(const float4*)(rp + 36);
    Af[i][0] = pack8(a0, a1);
    Af[i][1] = pack8(b0, b1);
  }

  float st = 0.f;
  #pragma unroll
  for (int half = 0; half < 2; ++half) {
    // ---- GEMM^T: leaf-tiles {2*half, 2*half+1} x row-tiles 0..3.
    // Lane l gets leaves (lt*16 + q*4 .. +3) of batch row (rt*16 + c):
    // one float4 LDS write per D-tile.
    #pragma unroll
    for (int rt = 0; rt < 4; ++rt) {
      #pragma unroll
      for (int lt = 0; lt < 2; ++lt) {
        f32x4 acc = {0.f, 0.f, 0.f, 0.f};
        acc = __builtin_amdgcn_mfma_f32_16x16x32_bf16(Bf[0][(half<<1)+lt], Af[rt][0], acc, 0, 0, 0);
        acc = __builtin_amdgcn_mfma_f32_16x16x32_bf16(Bf[1][(half<<1)+lt], Af[rt][1], acc, 0, 0, 0);
        const int row  = (w << 6) + (rt << 4) + c;     // block-local batch row
        const int nloc = (lt << 4) + (q << 2);         // local leaf 0..28
        *(f32x4*)&Lv[row * 36 + nloc] = acc;           // ds_write_b128, 2-way
      }
    }
    // ---- own row -> registers (8x ds_read_b128; wave-local ordering, no
    // barrier: same-wave DS ops complete in order via lgkmcnt).
    f32x4 Lf[8];
    #pragma unroll
    for (int i = 0; i < 8; ++i)
      Lf[i] = *(f32x4*)&Lv[tid * 36 + (i << 2)];

    // ---- register-only F chain.
    if (half == 0) {
      st = Lf[0][0];
      #pragma unroll
      for (int j = 1; j < 32; ++j)
        st = F_step(st, Lf[j >> 2][j & 3], layers + (j - 1) * 8);
    } else {
      #pragma unroll
      for (int j = 32; j < 64; ++j) {
        const int jl = j - 32;
        st = F_step(st, Lf[jl >> 2][jl & 3], layers + (j - 1) * 8);
      }
    }
  }

  out[rowbase + tid] = st;
}

// ---------------------------------------------------------------------------
extern "C" void kernel_launch(void* const* d_in, const int* in_sizes, int n_in,
                              void* d_out, int out_size, void* d_ws, size_t ws_size,
                              hipStream_t stream) {
  const float* x       = (const float*)d_in[0];
  const float* logits  = (const float*)d_in[1];
  const float* weights = (const float*)d_in[2];
  const float* biases  = (const float*)d_in[3];
  float* out = (float*)d_out;

  unsigned short* Pfrag = (unsigned short*)d_ws;              // 8 KB
  float* layers = (float*)((char*)d_ws + 8 * 64 * 8 * sizeof(unsigned short));

  const int batch = out_size;  // 262144

  hipLaunchKernelGGL(sinkhorn_kernel, dim3(1), dim3(64), 0, stream,
                     logits, weights, biases, Pfrag, layers);
  hipLaunchKernelGGL(scan_kernel, dim3(batch / 256), dim3(256), 0, stream,
                     x, Pfrag, layers, out);
}